// Round 12
// baseline (53.042 us; speedup 1.0000x reference)
//
#include <hip/hip_runtime.h>

// LVAE_shGLM encoder, fused bf16-MFMA implementation for gfx950.
// Round 12: LDS-throughput attack. Cycle model of r11: LDS unit ~64K cyc/CU
// (A-frag reads duplicated 8x by ct=1 col-split waves) vs MFMA 6.5K. New
// shape: 4 waves as 2x2 grid (wr row-half x wc col-half), wave owns 64t x
// 128n -> acc[2][4] f32x16; per kt 2 A-reads + 4 B-globals feed 8 MFMAs
// (A-reuse 4x, B-reuse 2x). Block LDS reads 1056 -> ~360 b128; B stays on
// the VMEM pipe (L2) to balance the two units. All frag machinery (Vdup
// mod-8 window, 32x32 layouts, uniform MFMAs) carried from verified r10/r11.
//
//   h_mid  = relu(windows @ W1 + b1)   windows[t,k] = pad[t+k]
//   mu_mid = h_mid @ W2 + b2           -> out[:, 0:4]
//   h_leaf = relu(h_mid @ Wl1 + bl1)
//   mu_leaf= h_leaf @ Wl2 + bl2        -> out[:, 4:20]

typedef __bf16 bf16;
typedef __bf16 bf16x8 __attribute__((ext_vector_type(8)));
typedef float  f32x4  __attribute__((ext_vector_type(4)));
typedef float  f32x16 __attribute__((ext_vector_type(16)));

constexpr int T_DATA = 100000;
constexpr int T_V    = 100;
constexpr int WIN    = 199;   // 2*T_V - 1
constexpr int HID    = 256;
constexpr int BT     = 128;   // timesteps per block
constexpr int HSTR   = 264;   // h-buffer row stride (elems); 528B (16B-aligned)
constexpr int VLEN   = 352;   // window span: 128 rows + 207 max k + 8 frag + pad
constexpr int VSTR   = 360;   // Vdup row stride (720B, 16B-aligned)

// ws layout in bf16 elements (written by pack_weights), 1KB groups:
//   [0*512     ..) PW1_32   13 kt(K=16) x 8 nt(32 cols)  = 104 groups (k>=199 zeroed)
//   [104*512   ..) PWL1_32  16 kt x 8 nt                 = 128 groups
//   [232*512   ..) PW2      8 kt(K=32), 16x16 frag, cols 0..3 real
//   [240*512   ..) PWL2     8 kt(K=32), 16x16 frag, 16 cols
constexpr int PWL1_OFF = 104 * 512;
constexpr int PW2_OFF  = 232 * 512;
constexpr int PWL2_OFF = 240 * 512;   // total 248 KB <= ws

__global__ void pack_weights(const float* __restrict__ W1, const float* __restrict__ W2,
                             const float* __restrict__ Wl1, const float* __restrict__ Wl2,
                             bf16* __restrict__ ws) {
  const int gid  = blockIdx.x * blockDim.x + threadIdx.x;  // [0, 15872)
  const int lane = gid & 63;
  const int grp  = gid >> 6;        // [0, 248)
  bf16x8 v;
  if (grp < 104) {                  // PW1_32: 32x32x16 B frag: col=lane&31, k=(lane>>5)*8+j
    const int kt = grp >> 3, nt = grp & 7, n = nt * 32 + (lane & 31);
#pragma unroll
    for (int j = 0; j < 8; ++j) {
      const int k = kt * 16 + (lane >> 5) * 8 + j;
      v[j] = (k < WIN) ? (bf16)W1[k * HID + n] : (bf16)0.0f;
    }
  } else if (grp < 232) {           // PWL1_32
    const int q = grp - 104;
    const int kt = q >> 3, nt = q & 7, n = nt * 32 + (lane & 31);
#pragma unroll
    for (int j = 0; j < 8; ++j) {
      const int k = kt * 16 + (lane >> 5) * 8 + j;
      v[j] = (bf16)Wl1[k * HID + n];
    }
  } else if (grp < 240) {           // PW2: 16x16x32 frag: col=lane&15, k=(lane>>4)*8+j
    const int kt = grp - 232, m = lane & 15;
#pragma unroll
    for (int j = 0; j < 8; ++j) {
      const int k = kt * 32 + (lane >> 4) * 8 + j;
      v[j] = (m < 4) ? (bf16)W2[k * 4 + m] : (bf16)0.0f;
    }
  } else {                          // PWL2
    const int kt = grp - 240, m = lane & 15;
#pragma unroll
    for (int j = 0; j < 8; ++j) {
      const int k = kt * 32 + (lane >> 4) * 8 + j;
      v[j] = (bf16)Wl2[k * 16 + m];
    }
  }
  *reinterpret_cast<bf16x8*>(ws + (size_t)gid * 8) = v;
}

__global__ __launch_bounds__(256, 2) void fused_enc(
    const float* __restrict__ V, const float* __restrict__ b1,
    const float* __restrict__ b2, const float* __restrict__ bl1,
    const float* __restrict__ bl2, const bf16* __restrict__ ws,
    float* __restrict__ out) {
  __shared__ bf16 Vdup[8][VSTR];    // 5.8 KB: Vdup[p][q] = pad[t0-99+q+p]
  __shared__ bf16 hbuf[BT * HSTR];  // 67.6 KB: h_mid, then h_leaf (WAR barrier)
  // total 73344 B -> 2 blocks/CU

  const int tid  = threadIdx.x;
  const int lane = tid & 63;
  const int w    = tid >> 6;            // wave id [0,4)
  const int wr   = w >> 1;              // row half: rows wr*64 .. wr*64+63
  const int wc   = w & 1;               // col half: cols wc*128 .. wc*128+127
  const int c5   = lane & 31;           // 32x32 frag col/row index
  const int hi   = lane >> 5;           // 32x32 frag k-half
  const int m    = lane & 15;           // 16x16 frag index
  const int g    = lane >> 4;           // 16x16 k-group
  const long t0  = (long)blockIdx.x * BT;

  // ---- 1. stage 8 shifted bf16 window copies ----
  for (int c = tid; c < 8 * VLEN; c += 256) {
    const int p = c / VLEN, q = c - p * VLEN;
    const long src = t0 + q + p - (T_V - 1);
    const float v = (src >= 0 && src < T_DATA) ? V[src] : 0.0f;
    Vdup[p][q] = (bf16)v;
  }
  __syncthreads();   // B0

  // A-frag element s = (wr*64 + rt*32 + c5) + kt*16 + hi*8 + j; s mod 8 = lane&7
  // (wr*64, rt*32 are 0 mod 8) -> copy p = lane&7 gives one aligned b128 read.
  const int p  = lane & 7;
  const int qb = (c5 + hi * 8) - p + wr * 64;  // aligned base within Vdup row p
  const bf16* vrow = &Vdup[p][0];

  f32x16 acc[2][4];                     // [rt][c]: rows wr*64+rt*32+.., cols wc*128+c*32+c5
#pragma unroll
  for (int rt = 0; rt < 2; ++rt)
#pragma unroll
    for (int c = 0; c < 4; ++c) acc[rt][c] = (f32x16){};

  // ---- 2. GEMM1: h_mid(pre) = windows @ W1, 13 kt of K=16 ----
#pragma unroll
  for (int kt = 0; kt < 13; ++kt) {
    bf16x8 bfr[4];
#pragma unroll
    for (int c = 0; c < 4; ++c)
      bfr[c] = *reinterpret_cast<const bf16x8*>(
          ws + (size_t)(kt * 8 + wc * 4 + c) * 512 + lane * 8);
#pragma unroll
    for (int rt = 0; rt < 2; ++rt) {
      const bf16x8 a = *reinterpret_cast<const bf16x8*>(vrow + qb + rt * 32 + kt * 16);
#pragma unroll
      for (int c = 0; c < 4; ++c)
        acc[rt][c] = __builtin_amdgcn_mfma_f32_32x32x16_bf16(a, bfr[c], acc[rt][c], 0, 0, 0);
    }
  }

  // ---- 3. h_mid epilogue: bias+relu -> hbuf ----
  // C/D 32x32 layout: col = lane&31, row = (r&3) + 8*(r>>2) + 4*(lane>>5)
#pragma unroll
  for (int c = 0; c < 4; ++c) {
    const int col = wc * 128 + c * 32 + c5;
    const float bb = b1[col];
#pragma unroll
    for (int rt = 0; rt < 2; ++rt)
#pragma unroll
      for (int r = 0; r < 16; ++r) {
        const int row = wr * 64 + rt * 32 + (r & 3) + 8 * (r >> 2) + 4 * hi;
        hbuf[row * HSTR + col] = (bf16)fmaxf(acc[rt][c][r] + bb, 0.0f);
      }
  }
  __syncthreads();   // B1: h_mid visible

  // ---- 4. GEMM3: h_leaf(pre) = h_mid @ Wl1, 16 kt of K=16 ----
#pragma unroll
  for (int rt = 0; rt < 2; ++rt)
#pragma unroll
    for (int c = 0; c < 4; ++c) acc[rt][c] = (f32x16){};
#pragma unroll
  for (int kt = 0; kt < 16; ++kt) {
    bf16x8 bfr[4];
#pragma unroll
    for (int c = 0; c < 4; ++c)
      bfr[c] = *reinterpret_cast<const bf16x8*>(
          ws + PWL1_OFF + (size_t)(kt * 8 + wc * 4 + c) * 512 + lane * 8);
    const int koff = kt * 16 + hi * 8;
#pragma unroll
    for (int rt = 0; rt < 2; ++rt) {
      const bf16x8 a = *reinterpret_cast<const bf16x8*>(
          &hbuf[(wr * 64 + rt * 32 + c5) * HSTR + koff]);
#pragma unroll
      for (int c = 0; c < 4; ++c)
        acc[rt][c] = __builtin_amdgcn_mfma_f32_32x32x16_bf16(a, bfr[c], acc[rt][c], 0, 0, 0);
    }
  }

  // ---- 4b. mu_mid: wave w handles row-groups {2w, 2w+1} (rows 32w..32w+31) ----
  f32x4 mu2a[2] = {(f32x4){0.f, 0.f, 0.f, 0.f}, (f32x4){0.f, 0.f, 0.f, 0.f}};
#pragma unroll
  for (int kt = 0; kt < 8; ++kt) {
    const bf16x8 bw2 = *reinterpret_cast<const bf16x8*>(
        ws + PW2_OFF + (size_t)kt * 512 + lane * 8);
#pragma unroll
    for (int q = 0; q < 2; ++q) {
      const bf16x8 a = *reinterpret_cast<const bf16x8*>(
          &hbuf[(w * 32 + q * 16 + m) * HSTR + kt * 32 + g * 8]);
      mu2a[q] = __builtin_amdgcn_mfma_f32_16x16x32_bf16(a, bw2, mu2a[q], 0, 0, 0);
    }
  }
  {
    const float b2v = (m < 4) ? b2[m] : 0.0f;
#pragma unroll
    for (int q = 0; q < 2; ++q)
#pragma unroll
      for (int j = 0; j < 4; ++j) {     // C 16x16: col=lane&15, row=(lane>>4)*4+reg
        const long t = t0 + w * 32 + q * 16 + g * 4 + j;
        if (t < T_DATA && m < 4) out[t * 20 + m] = mu2a[q][j] + b2v;
      }
  }
  __syncthreads();   // B2 (WAR): all h_mid reads done before h_leaf overwrite

  // ---- 5. h_leaf epilogue: bias+relu -> hbuf ----
#pragma unroll
  for (int c = 0; c < 4; ++c) {
    const int col = wc * 128 + c * 32 + c5;
    const float bb = bl1[col];
#pragma unroll
    for (int rt = 0; rt < 2; ++rt)
#pragma unroll
      for (int r = 0; r < 16; ++r) {
        const int row = wr * 64 + rt * 32 + (r & 3) + 8 * (r >> 2) + 4 * hi;
        hbuf[row * HSTR + col] = (bf16)fmaxf(acc[rt][c][r] + bb, 0.0f);
      }
  }
  __syncthreads();   // B3: h_leaf visible

  // ---- 6. mu_leaf: wave w handles row-groups {2w, 2w+1} ----
  f32x4 mu4a[2] = {(f32x4){0.f, 0.f, 0.f, 0.f}, (f32x4){0.f, 0.f, 0.f, 0.f}};
#pragma unroll
  for (int kq = 0; kq < 8; ++kq) {
    const bf16x8 b = *reinterpret_cast<const bf16x8*>(
        ws + PWL2_OFF + (size_t)kq * 512 + lane * 8);
#pragma unroll
    for (int q = 0; q < 2; ++q) {
      const bf16x8 a = *reinterpret_cast<const bf16x8*>(
          &hbuf[(w * 32 + q * 16 + m) * HSTR + kq * 32 + g * 8]);
      mu4a[q] = __builtin_amdgcn_mfma_f32_16x16x32_bf16(a, b, mu4a[q], 0, 0, 0);
    }
  }
  {
    const float blv = bl2[m];
#pragma unroll
    for (int q = 0; q < 2; ++q)
#pragma unroll
      for (int j = 0; j < 4; ++j) {
        const long t = t0 + w * 32 + q * 16 + g * 4 + j;
        if (t < T_DATA) out[t * 20 + 4 + m] = mu4a[q][j] + blv;
      }
  }
}

extern "C" void kernel_launch(void* const* d_in, const int* in_sizes, int n_in,
                              void* d_out, int out_size, void* d_ws, size_t ws_size,
                              hipStream_t stream) {
  const float* V   = (const float*)d_in[0];
  const float* W1  = (const float*)d_in[1];
  const float* b1  = (const float*)d_in[2];
  const float* W2  = (const float*)d_in[3];
  const float* b2  = (const float*)d_in[4];
  const float* Wl1 = (const float*)d_in[5];
  const float* bl1 = (const float*)d_in[6];
  const float* Wl2 = (const float*)d_in[7];
  const float* bl2 = (const float*)d_in[8];
  bf16* ws = (bf16*)d_ws;   // needs 253952 bytes
  float* out = (float*)d_out;

  pack_weights<<<62, 256, 0, stream>>>(W1, W2, Wl1, Wl2, ws);

  const int grid = (T_DATA + BT - 1) / BT;   // 782
  fused_enc<<<grid, 256, 0, stream>>>(V, b1, b2, bl1, bl2, ws, out);
}

// Round 13
// 48.989 us; speedup vs baseline: 1.0827x; 1.0827x over previous
//
#include <hip/hip_runtime.h>

// LVAE_shGLM encoder, fused bf16-MFMA implementation for gfx950.
// Round 13: no-spill A-reuse. r12's 2x2 grid spilled (acc[2][4]=128 regs ->
// WRITE_SIZE 17.5MB); this is r11 with ONLY the wave grid changed 1x8 -> 2x4
// (wr row-half x wc 64-col stripe): acc[2][2] f32x16 = 64 regs (r11-proven
// budget, VGPR 52+64=116<=128) while halving LDS A-read duplication
// (each A ds_read_b128 feeds 2 MFMAs). B groups read by 2 waves (L1/L2
// absorbs; VMEM pipe overlaps LDS pipe). All else identical to r11.
//
//   h_mid  = relu(windows @ W1 + b1)   windows[t,k] = pad[t+k]
//   mu_mid = h_mid @ W2 + b2           -> out[:, 0:4]
//   h_leaf = relu(h_mid @ Wl1 + bl1)
//   mu_leaf= h_leaf @ Wl2 + bl2        -> out[:, 4:20]

typedef __bf16 bf16;
typedef __bf16 bf16x8 __attribute__((ext_vector_type(8)));
typedef float  f32x4  __attribute__((ext_vector_type(4)));
typedef float  f32x16 __attribute__((ext_vector_type(16)));

constexpr int T_DATA = 100000;
constexpr int T_V    = 100;
constexpr int WIN    = 199;   // 2*T_V - 1
constexpr int HID    = 256;
constexpr int BT     = 128;   // timesteps per block
constexpr int HSTR   = 264;   // h-buffer row stride (elems); 528B (16B-aligned)
constexpr int VLEN   = 352;   // window span: 128 rows + 207 max k + 8 frag + pad
constexpr int VSTR   = 360;   // Vdup row stride (720B, 16B-aligned)

// ws layout in bf16 elements (written by pack_weights), 1KB groups:
//   [0*512     ..) PW1_32   13 kt(K=16) x 8 nt(32 cols)  = 104 groups (k>=199 zeroed)
//   [104*512   ..) PWL1_32  16 kt x 8 nt                 = 128 groups
//   [232*512   ..) PW2      8 kt(K=32), 16x16 frag, cols 0..3 real
//   [240*512   ..) PWL2     8 kt(K=32), 16x16 frag, 16 cols
constexpr int PWL1_OFF = 104 * 512;
constexpr int PW2_OFF  = 232 * 512;
constexpr int PWL2_OFF = 240 * 512;   // total 248 KB <= ws

__global__ void pack_weights(const float* __restrict__ W1, const float* __restrict__ W2,
                             const float* __restrict__ Wl1, const float* __restrict__ Wl2,
                             bf16* __restrict__ ws) {
  const int gid  = blockIdx.x * blockDim.x + threadIdx.x;  // [0, 15872)
  const int lane = gid & 63;
  const int grp  = gid >> 6;        // [0, 248)
  bf16x8 v;
  if (grp < 104) {                  // PW1_32: 32x32x16 B frag: col=lane&31, k=(lane>>5)*8+j
    const int kt = grp >> 3, nt = grp & 7, n = nt * 32 + (lane & 31);
#pragma unroll
    for (int j = 0; j < 8; ++j) {
      const int k = kt * 16 + (lane >> 5) * 8 + j;
      v[j] = (k < WIN) ? (bf16)W1[k * HID + n] : (bf16)0.0f;
    }
  } else if (grp < 232) {           // PWL1_32
    const int q = grp - 104;
    const int kt = q >> 3, nt = q & 7, n = nt * 32 + (lane & 31);
#pragma unroll
    for (int j = 0; j < 8; ++j) {
      const int k = kt * 16 + (lane >> 5) * 8 + j;
      v[j] = (bf16)Wl1[k * HID + n];
    }
  } else if (grp < 240) {           // PW2: 16x16x32 frag: col=lane&15, k=(lane>>4)*8+j
    const int kt = grp - 232, m = lane & 15;
#pragma unroll
    for (int j = 0; j < 8; ++j) {
      const int k = kt * 32 + (lane >> 4) * 8 + j;
      v[j] = (m < 4) ? (bf16)W2[k * 4 + m] : (bf16)0.0f;
    }
  } else {                          // PWL2
    const int kt = grp - 240, m = lane & 15;
#pragma unroll
    for (int j = 0; j < 8; ++j) {
      const int k = kt * 32 + (lane >> 4) * 8 + j;
      v[j] = (bf16)Wl2[k * 16 + m];
    }
  }
  *reinterpret_cast<bf16x8*>(ws + (size_t)gid * 8) = v;
}

__global__ __launch_bounds__(512, 4) void fused_enc(
    const float* __restrict__ V, const float* __restrict__ b1,
    const float* __restrict__ b2, const float* __restrict__ bl1,
    const float* __restrict__ bl2, const bf16* __restrict__ ws,
    float* __restrict__ out) {
  __shared__ bf16 Vdup[8][VSTR];    // 5.8 KB: Vdup[p][q] = pad[t0-99+q+p]
  __shared__ bf16 hbuf[BT * HSTR];  // 67.6 KB: h_mid, then h_leaf (WAR barrier)
  // total 73344 B -> 2 blocks/CU

  const int tid  = threadIdx.x;
  const int lane = tid & 63;
  const int w    = tid >> 6;            // wave id [0,8)
  const int wr   = w >> 2;              // row half: rows wr*64 .. wr*64+63
  const int wc   = w & 3;               // col stripe: cols wc*64 .. wc*64+63
  const int c5   = lane & 31;           // 32x32 frag col/row index
  const int hi   = lane >> 5;           // 32x32 frag k-half
  const int m    = lane & 15;           // 16x16 frag index
  const int g    = lane >> 4;           // 16x16 k-group
  const long t0  = (long)blockIdx.x * BT;

  // ---- 1. stage 8 shifted bf16 window copies ----
  for (int c = tid; c < 8 * VLEN; c += 512) {
    const int p = c / VLEN, q = c - p * VLEN;
    const long src = t0 + q + p - (T_V - 1);
    const float v = (src >= 0 && src < T_DATA) ? V[src] : 0.0f;
    Vdup[p][q] = (bf16)v;
  }
  __syncthreads();   // B0

  // A-frag element s = (wr*64 + rt*32 + c5) + kt*16 + hi*8 + j; s mod 8 = lane&7
  // (wr*64, rt*32 are 0 mod 8) -> copy p = lane&7 gives one aligned b128 read.
  const int p  = lane & 7;
  const int qb = (c5 + hi * 8) - p + wr * 64;  // aligned base within Vdup row p
  const bf16* vrow = &Vdup[p][0];

  f32x16 acc[2][2];   // [rt][c]: rows wr*64+rt*32+.., cols wc*64+c*32+c5
#pragma unroll
  for (int rt = 0; rt < 2; ++rt)
#pragma unroll
    for (int c = 0; c < 2; ++c) acc[rt][c] = (f32x16){};

  // ---- 2. GEMM1: h_mid(pre) = windows @ W1, 13 kt of K=16 ----
#pragma unroll
  for (int kt = 0; kt < 13; ++kt) {
    bf16x8 bfr[2];
#pragma unroll
    for (int c = 0; c < 2; ++c)
      bfr[c] = *reinterpret_cast<const bf16x8*>(
          ws + (size_t)(kt * 8 + wc * 2 + c) * 512 + lane * 8);
#pragma unroll
    for (int rt = 0; rt < 2; ++rt) {
      const bf16x8 a = *reinterpret_cast<const bf16x8*>(vrow + qb + rt * 32 + kt * 16);
#pragma unroll
      for (int c = 0; c < 2; ++c)
        acc[rt][c] = __builtin_amdgcn_mfma_f32_32x32x16_bf16(a, bfr[c], acc[rt][c], 0, 0, 0);
    }
  }

  // ---- 3. h_mid epilogue: bias+relu -> hbuf ----
  // C/D 32x32 layout: col = lane&31, row = (r&3) + 8*(r>>2) + 4*(lane>>5)
#pragma unroll
  for (int c = 0; c < 2; ++c) {
    const int col = wc * 64 + c * 32 + c5;
    const float bb = b1[col];
#pragma unroll
    for (int rt = 0; rt < 2; ++rt)
#pragma unroll
      for (int r = 0; r < 16; ++r) {
        const int row = wr * 64 + rt * 32 + (r & 3) + 8 * (r >> 2) + 4 * hi;
        hbuf[row * HSTR + col] = (bf16)fmaxf(acc[rt][c][r] + bb, 0.0f);
      }
  }
  __syncthreads();   // B1: h_mid visible

  // ---- 4. GEMM3: h_leaf(pre) = h_mid @ Wl1, 16 kt of K=16 ----
#pragma unroll
  for (int rt = 0; rt < 2; ++rt)
#pragma unroll
    for (int c = 0; c < 2; ++c) acc[rt][c] = (f32x16){};
#pragma unroll
  for (int kt = 0; kt < 16; ++kt) {
    bf16x8 bfr[2];
#pragma unroll
    for (int c = 0; c < 2; ++c)
      bfr[c] = *reinterpret_cast<const bf16x8*>(
          ws + PWL1_OFF + (size_t)(kt * 8 + wc * 2 + c) * 512 + lane * 8);
    const int koff = kt * 16 + hi * 8;
#pragma unroll
    for (int rt = 0; rt < 2; ++rt) {
      const bf16x8 a = *reinterpret_cast<const bf16x8*>(
          &hbuf[(wr * 64 + rt * 32 + c5) * HSTR + koff]);
#pragma unroll
      for (int c = 0; c < 2; ++c)
        acc[rt][c] = __builtin_amdgcn_mfma_f32_32x32x16_bf16(a, bfr[c], acc[rt][c], 0, 0, 0);
    }
  }

  // ---- 4b. mu_mid: wave w handles rows w*16 .. w*16+15 (reads h_mid) ----
  f32x4 mu = {0.f, 0.f, 0.f, 0.f};
#pragma unroll
  for (int kt = 0; kt < 8; ++kt) {
    const bf16x8 a = *reinterpret_cast<const bf16x8*>(
        &hbuf[(w * 16 + m) * HSTR + kt * 32 + g * 8]);
    const bf16x8 b = *reinterpret_cast<const bf16x8*>(
        ws + PW2_OFF + (size_t)kt * 512 + lane * 8);
    mu = __builtin_amdgcn_mfma_f32_16x16x32_bf16(a, b, mu, 0, 0, 0);
  }
  {
    const float b2v = (m < 4) ? b2[m] : 0.0f;
#pragma unroll
    for (int j = 0; j < 4; ++j) {       // C 16x16: col=lane&15, row=(lane>>4)*4+reg
      const long t = t0 + w * 16 + g * 4 + j;
      if (t < T_DATA && m < 4) out[t * 20 + m] = mu[j] + b2v;
    }
  }
  __syncthreads();   // B2 (WAR): all h_mid reads done before h_leaf overwrite

  // ---- 5. h_leaf epilogue: bias+relu -> hbuf ----
#pragma unroll
  for (int c = 0; c < 2; ++c) {
    const int col = wc * 64 + c * 32 + c5;
    const float bb = bl1[col];
#pragma unroll
    for (int rt = 0; rt < 2; ++rt)
#pragma unroll
      for (int r = 0; r < 16; ++r) {
        const int row = wr * 64 + rt * 32 + (r & 3) + 8 * (r >> 2) + 4 * hi;
        hbuf[row * HSTR + col] = (bf16)fmaxf(acc[rt][c][r] + bb, 0.0f);
      }
  }
  __syncthreads();   // B3: h_leaf visible

  // ---- 6. mu_leaf: wave w handles rows w*16 .. w*16+15 ----
  mu = (f32x4){0.f, 0.f, 0.f, 0.f};
#pragma unroll
  for (int kq = 0; kq < 8; ++kq) {
    const bf16x8 a = *reinterpret_cast<const bf16x8*>(
        &hbuf[(w * 16 + m) * HSTR + kq * 32 + g * 8]);
    const bf16x8 b = *reinterpret_cast<const bf16x8*>(
        ws + PWL2_OFF + (size_t)kq * 512 + lane * 8);
    mu = __builtin_amdgcn_mfma_f32_16x16x32_bf16(a, b, mu, 0, 0, 0);
  }
  {
    const float blv = bl2[m];
#pragma unroll
    for (int j = 0; j < 4; ++j) {
      const long t = t0 + w * 16 + g * 4 + j;
      if (t < T_DATA) out[t * 20 + 4 + m] = mu[j] + blv;
    }
  }
}

extern "C" void kernel_launch(void* const* d_in, const int* in_sizes, int n_in,
                              void* d_out, int out_size, void* d_ws, size_t ws_size,
                              hipStream_t stream) {
  const float* V   = (const float*)d_in[0];
  const float* W1  = (const float*)d_in[1];
  const float* b1  = (const float*)d_in[2];
  const float* W2  = (const float*)d_in[3];
  const float* b2  = (const float*)d_in[4];
  const float* Wl1 = (const float*)d_in[5];
  const float* bl1 = (const float*)d_in[6];
  const float* Wl2 = (const float*)d_in[7];
  const float* bl2 = (const float*)d_in[8];
  bf16* ws = (bf16*)d_ws;   // needs 253952 bytes
  float* out = (float*)d_out;

  pack_weights<<<62, 256, 0, stream>>>(W1, W2, Wl1, Wl2, ws);

  const int grid = (T_DATA + BT - 1) / BT;   // 782
  fused_enc<<<grid, 512, 0, stream>>>(V, b1, b2, bl1, bl2, ws, out);
}